// Round 8
// baseline (442.692 us; speedup 1.0000x reference)
//
#include <hip/hip_runtime.h>

// PoolHiddenNet round 16: "pool_tile32" -- A-full-K-in-LDS (converted once)
// + r8's proven DMA-dbuf lockstep for B.
// r15 post-mortem: doubling occupancy (21->38%) changed NOTHING (195->196us);
// with MFMA=VALU=14%, HBM=8%, the reg-staged barrier-free loop runs its
// phases as serial bursts (all waves same code, same start): serial sum of
// pipe floors ~= 190us. The structure that avoided this was r5/r8's DMA
// lockstep (139us): staging lives in the DMA engine, waves only ds_read+MFMA,
// distance-1 barriers keep DMA streaming. This round fuses that with the
// A-in-LDS trick:
//  - block = 32 rows x 256 cols, 256 thr, 4 waves (wave = 32x64, acc[2][4]).
//  - A panel 32 rows x 640 K bf16 = 40KB, converted fp32->bf16 ONCE in the
//    prologue (emb computed there too). No per-kt A staging at all.
//  - B per-kt DMA double-buffer 2x16KB from L2-hot WmT (640KB), 4
//    global_load_lds per wave per kt, pre-swizzled source (r8 algebra).
//  - LDS 72KB -> 2 blocks/CU: conversion of block n+1 overlaps K-loop of n.
//  - 32-row window crosses <=1 group boundary -> 2-segment reg epilogue.
//  - col-siblings share XCD (r12 bid map) -> duplicated fp32 A read = L2 hit.

typedef __bf16 bf16x8 __attribute__((ext_vector_type(8)));
typedef float floatx4 __attribute__((ext_vector_type(4)));

constexpr int NR = 102400;
constexpr int NG = 2048;
constexpr int E  = 128;
constexpr int H  = 512;
constexpr int KD = 640;
constexpr int BM = 128, BN = 128, BK = 32;   // fallback tile
constexpr int NKT = KD / BK;   // 20
constexpr int RB  = 32;        // rows per block
constexpr int CB  = 256;       // cols per block

__device__ inline unsigned short f2bf(float f) {
    unsigned u = __float_as_uint(f);
    u += 0x7FFF + ((u >> 16) & 1u);   // RNE (finite inputs)
    return (unsigned short)(u >> 16);
}

// pack two fp32 -> bf16x2, round-half-up: 2x v_add + 1x v_perm_b32
__device__ inline unsigned pk2(float lo, float hi) {
    return __builtin_amdgcn_perm(__float_as_uint(hi) + 0x8000u,
                                 __float_as_uint(lo) + 0x8000u, 0x07060302u);
}

__device__ inline void async16(const void* g, void* l) {
    __builtin_amdgcn_global_load_lds(
        (const __attribute__((address_space(1))) unsigned int*)g,
        (__attribute__((address_space(3))) unsigned int*)l, 16, 0, 0);
}

// ---------------- prep: segArr + relA (400 blocks) + WmT transpose (80) ----------------
__global__ __launch_bounds__(256) void prep3(
    const float* __restrict__ pos, const int* __restrict__ sse,
    const float* __restrict__ Wm, unsigned short* __restrict__ WmT,
    int* __restrict__ segArr, float* __restrict__ relA)
{
    const int b = blockIdx.x;
    const int t = threadIdx.x;
    __shared__ float tile[64][65];
    if (b < 400) {
        if (!segArr) return;
        const int i = b * 256 + t;
        int l = 0, r = NG + 1;
        while (l < r) { int m = (l + r) >> 1; if (sse[m] <= i) l = m + 1; else r = m; }
        const int g = l - 1;
        segArr[i] = g;
        const int a = sse[g];
        relA[2 * i + 0] = pos[2 * i + 0] - pos[2 * a + 0];
        relA[2 * i + 1] = pos[2 * i + 1] - pos[2 * a + 1];
    } else {
        const int bb = b - 400;             // [0,80): Wm (640x512) -> WmT (512x640) bf16
        const int kb = (bb % 10) * 64, nb = (bb / 10) * 64;
        const int tx = t & 63, tq = t >> 6;
#pragma unroll
        for (int i = 0; i < 16; ++i) {
            const int k = tq * 16 + i;
            tile[k][tx] = Wm[(size_t)(kb + k) * H + nb + tx];
        }
        __syncthreads();
#pragma unroll
        for (int i = 0; i < 16; ++i) {
            const int n = tq * 16 + i;
            WmT[(size_t)(nb + n) * KD + kb + tx] = f2bf(tile[tx][n]);
        }
    }
}

// ---------------- main: 32x256 tile, A-LDS full-K once, B DMA-dbuf lockstep ----------------
__global__ __launch_bounds__(256, 2) void pool_tile32(
    const float* __restrict__ hist_enc,       // (NR, 512) fp32
    const int*   __restrict__ sse,
    const int*   __restrict__ segArr,         // (NR,)
    const float* __restrict__ relA,           // (NR, 2) fp32
    const float* __restrict__ Ws,             // (2, 128)
    const float* __restrict__ bs,             // (128,)
    const unsigned short* __restrict__ WmT,   // (512, 640) bf16
    const float* __restrict__ bm,             // (512,)
    float*       __restrict__ out)            // (2048, 512) fp32, zeroed
{
    // A panel: 20 k-tiles x 32 rows x 32 k bf16 = 40960 B (XOR slot keyed on row).
    __shared__ __attribute__((aligned(16))) unsigned short As[NKT * RB * 32];
    // B double buffer: 2 x (256 cols x 32 k) bf16 = 2 x 16384 B.
    __shared__ __attribute__((aligned(16))) unsigned short Bs2[2][CB * 32];

    const int t   = threadIdx.x;
    const int bid = blockIdx.x;              // [0,6400)
    // r12-proven map: col-siblings of a chunk differ by 8 in bid -> same XCD.
    const int x       = bid & 7;
    const int q       = bid >> 3;            // [0,800)
    const int colTile = q & 1;
    const int chunk   = (q >> 1) * 8 + x;    // [0,3200)
    const int rowBase = chunk * RB;
    const int cTile   = colTile * CB;

    const int lane  = t & 63;
    const int wv    = t >> 6;                // 4 waves; wave = 32 rows x 64 cols
    const int lcol  = lane & 15;
    const int lquad = lane >> 4;

    // ---- B DMA pointers: wave wv stages cols [wv*64, wv*64+64), 4 instrs ----
    // lane -> colOff = lane>>2, phys = lane&3; source chunk pre-XOR-swizzled.
    const unsigned short* gB[4];
#pragma unroll
    for (int s = 0; s < 4; ++s) {
        const int colL = wv * 64 + s * 16 + (lane >> 2);
        const int cl   = (lane & 3) ^ ((colL >> 1) & 3);
        gB[s] = WmT + (size_t)(cTile + colL) * KD + cl * 8;
    }
    auto issueB = [&](int kt, int buf) {
        const int ko = kt * BK;
#pragma unroll
        for (int s = 0; s < 4; ++s)
            async16(gB[s] + ko, &Bs2[buf][(wv * 4 + s) * 512]);
    };

    issueB(0, 0);   // streams during the conversion phase

    // ---- conversion phase: 32 rows x 640 K -> As (once) ----
    // thread t: row t>>3 (0..31), phys t&7; 8 hist chunks + 2 emb chunks.
    {
        const int row  = t >> 3;
        const int phys = t & 7;
        const int swz  = (row >> 1) & 3;
        const float* src = hist_enc + (size_t)(rowBase + row) * H + phys * 8;
#pragma unroll
        for (int p = 0; p < 8; ++p) {
            const int c8 = p * 8 + phys;              // [0,64)
            const float4 f0 = *(const float4*)(src + p * 64);
            const float4 f1 = *(const float4*)(src + p * 64 + 4);
            uint4 u;
            u.x = pk2(f0.x, f0.y); u.y = pk2(f0.z, f0.w);
            u.z = pk2(f1.x, f1.y); u.w = pk2(f1.z, f1.w);
            const int kt = c8 >> 2, slot = (c8 & 3) ^ swz;
            *(uint4*)&As[kt * 1024 + row * 32 + slot * 8] = u;
        }
        const float2 rr = *(const float2*)&relA[2 * (size_t)(rowBase + row)];
#pragma unroll
        for (int p = 0; p < 2; ++p) {
            const int ce = p * 8 + phys;              // [0,16)
            const int e0 = ce * 8;                    // [0,128)
            const float4 w0a = *(const float4*)&Ws[e0];
            const float4 w0b = *(const float4*)&Ws[e0 + 4];
            const float4 w1a = *(const float4*)&Ws[E + e0];
            const float4 w1b = *(const float4*)&Ws[E + e0 + 4];
            const float4 ba4 = *(const float4*)&bs[e0];
            const float4 bb4 = *(const float4*)&bs[e0 + 4];
            float4 fa, fb;
            fa.x = fmaxf(rr.x * w0a.x + rr.y * w1a.x + ba4.x, 0.f);
            fa.y = fmaxf(rr.x * w0a.y + rr.y * w1a.y + ba4.y, 0.f);
            fa.z = fmaxf(rr.x * w0a.z + rr.y * w1a.z + ba4.z, 0.f);
            fa.w = fmaxf(rr.x * w0a.w + rr.y * w1a.w + ba4.w, 0.f);
            fb.x = fmaxf(rr.x * w0b.x + rr.y * w1b.x + bb4.x, 0.f);
            fb.y = fmaxf(rr.x * w0b.y + rr.y * w1b.y + bb4.y, 0.f);
            fb.z = fmaxf(rr.x * w0b.z + rr.y * w1b.z + bb4.z, 0.f);
            fb.w = fmaxf(rr.x * w0b.w + rr.y * w1b.w + bb4.w, 0.f);
            uint4 u;
            u.x = pk2(fa.x, fa.y); u.y = pk2(fa.z, fa.w);
            u.z = pk2(fb.x, fb.y); u.w = pk2(fb.z, fb.w);
            const int kt = 16 + (ce >> 2), slot = (ce & 3) ^ swz;
            *(uint4*)&As[kt * 1024 + row * 32 + slot * 8] = u;
        }
    }

    // per-lane epilogue constants (overlap conversion)
    float bias[4];
#pragma unroll
    for (int nt = 0; nt < 4; ++nt) bias[nt] = bm[cTile + wv * 64 + nt * 16 + lcol];
    const int s0 = segArr[rowBase];               // block-uniform
    const int bA = sse[s0 + 1];                   // 32-row window: <=1 boundary

    floatx4 acc[2][4];
#pragma unroll
    for (int m = 0; m < 2; ++m)
#pragma unroll
        for (int n = 0; n < 4; ++n) acc[m][n] = (floatx4){0.f, 0.f, 0.f, 0.f};

    // ---- K loop: r5/r8-proven distance-1 DMA lockstep (B only) ----
    for (int kt = 0; kt < NKT; ++kt) {
        __syncthreads();                     // drains B DMA(kt) + conv writes (kt=0)
        if (kt + 1 < NKT) issueB(kt + 1, (kt + 1) & 1);

        const unsigned short* B = Bs2[kt & 1];
        bf16x8 af[2], bfr[4];
#pragma unroll
        for (int mt = 0; mt < 2; ++mt) {
            const int R  = mt * 16 + lcol;
            const int pc = lquad ^ ((R >> 1) & 3);
            af[mt] = *(const bf16x8*)&As[kt * 1024 + R * 32 + pc * 8];
        }
#pragma unroll
        for (int nt = 0; nt < 4; ++nt) {
            const int c  = wv * 64 + nt * 16 + lcol;
            const int pc = lquad ^ ((c >> 1) & 3);
            bfr[nt] = *(const bf16x8*)&B[c * 32 + pc * 8];
        }
#pragma unroll
        for (int mt = 0; mt < 2; ++mt)
#pragma unroll
            for (int nt = 0; nt < 4; ++nt)
                acc[mt][nt] = __builtin_amdgcn_mfma_f32_16x16x32_bf16(af[mt], bfr[nt], acc[mt][nt], 0, 0, 0);
    }

    // ---- epilogue: per-wave reg reduce, 2 segments, global atomicMax ----
    float pm0[4] = {0.f, 0.f, 0.f, 0.f};
    float pm1[4] = {0.f, 0.f, 0.f, 0.f};
#pragma unroll
    for (int nt = 0; nt < 4; ++nt) {
#pragma unroll
        for (int mt = 0; mt < 2; ++mt) {
#pragma unroll
            for (int rr = 0; rr < 4; ++rr) {
                const int rowAbs = rowBase + mt * 16 + lquad * 4 + rr;
                const float v = fmaxf(acc[mt][nt][rr] + bias[nt], 0.f);
                const bool geA = rowAbs >= bA;
                pm0[nt] = fmaxf(pm0[nt], (!geA) ? v : 0.f);
                pm1[nt] = fmaxf(pm1[nt], ( geA) ? v : 0.f);
            }
        }
    }
#pragma unroll
    for (int s = 0; s < 2; ++s) {
#pragma unroll
        for (int nt = 0; nt < 4; ++nt) {
            float v = (s == 0) ? pm0[nt] : pm1[nt];
            v = fmaxf(v, __shfl_xor(v, 16));
            v = fmaxf(v, __shfl_xor(v, 32));
            if (lquad == 0 && v > 0.f) {
                float* dst = &out[(size_t)(s0 + s) * H + cTile + wv * 64 + nt * 16 + lcol];
                atomicMax((int*)dst, __float_as_int(v));
            }
        }
    }
}

// ---------------- fallback (round-2 kernel; only if ws too small) ----------------
constexpr int LDAF = 40;
__global__ __launch_bounds__(256) void pool_mfma_fb(
    const float* __restrict__ hist_enc, const float* __restrict__ pos,
    const int* __restrict__ sse, const float* __restrict__ Ws,
    const float* __restrict__ bs, const unsigned short* __restrict__ WmT,
    const float* __restrict__ bm, float* __restrict__ out)
{
    __shared__ __attribute__((aligned(16))) unsigned short Asf[BM][LDAF];
    __shared__ __attribute__((aligned(16))) unsigned short Bsb[BN][LDAF];
    __shared__ float relRow[BM][2];
    __shared__ int   segRow[BM];
    __shared__ int   bnd[3];
    __shared__ int   Pmax[4][BN + 4];

    const int t = threadIdx.x;
    const int cTile = blockIdx.x * BN;
    const int rowBase = blockIdx.y * BM;

    if (t < BM) {
        const int i = rowBase + t;
        int l = 0, r = NG + 1;
        while (l < r) { int m = (l + r) >> 1; if (sse[m] <= i) l = m + 1; else r = m; }
        const int g = l - 1;
        segRow[t] = g;
        const int a = sse[g];
        relRow[t][0] = pos[2 * i + 0] - pos[2 * a + 0];
        relRow[t][1] = pos[2 * i + 1] - pos[2 * a + 1];
    }
    if (t >= BM && t < BM + 3) bnd[t - BM] = BM;
    for (int idx = t; idx < 4 * (BN + 4); idx += 256) ((int*)Pmax)[idx] = 0;
    __syncthreads();
    if (t < BM - 1) {
        const int s0 = segRow[t], s1 = segRow[t + 1];
        if (s1 != s0) bnd[s1 - segRow[0] - 1] = t + 1;
    }

    const int lane = t & 63, wv = t >> 6;
    const int wr = (wv >> 1) * 64, wc = (wv & 1) * 64;
    const int lcol = lane & 15, lquad = lane >> 4;

    floatx4 acc[4][4];
#pragma unroll
    for (int m = 0; m < 4; ++m)
#pragma unroll
        for (int n = 0; n < 4; ++n) acc[m][n] = (floatx4){0.f, 0.f, 0.f, 0.f};

    for (int kt = 0; kt < KD / BK; ++kt) {
        const int k0 = kt * BK;
        float4 av[4]; uint4 bv[2];
        if (k0 < H) {
#pragma unroll
            for (int i = 0; i < 4; ++i) {
                const int idx = i * 256 + t;
                const int row = idx >> 3, kq = (idx & 7) * 4;
                av[i] = *(const float4*)&hist_enc[(size_t)(rowBase + row) * H + k0 + kq];
            }
        } else {
#pragma unroll
            for (int i = 0; i < 4; ++i) {
                const int idx = i * 256 + t;
                const int row = idx >> 3, kq = (idx & 7) * 4;
                const int e = k0 - H + kq;
                const float4 w0 = *(const float4*)&Ws[e];
                const float4 w1 = *(const float4*)&Ws[E + e];
                const float4 b4 = *(const float4*)&bs[e];
                const float r0 = relRow[row][0], r1 = relRow[row][1];
                av[i].x = fmaxf(r0 * w0.x + r1 * w1.x + b4.x, 0.f);
                av[i].y = fmaxf(r0 * w0.y + r1 * w1.y + b4.y, 0.f);
                av[i].z = fmaxf(r0 * w0.z + r1 * w1.z + b4.z, 0.f);
                av[i].w = fmaxf(r0 * w0.w + r1 * w1.w + b4.w, 0.f);
            }
        }
#pragma unroll
        for (int i = 0; i < 2; ++i) {
            const int idx = i * 256 + t;
            const int n = idx >> 2, q = idx & 3;
            bv[i] = *(const uint4*)&WmT[(size_t)(cTile + n) * KD + k0 + q * 8];
        }
        __syncthreads();
#pragma unroll
        for (int i = 0; i < 4; ++i) {
            const int idx = i * 256 + t;
            const int row = idx >> 3, kq = (idx & 7) * 4;
            ushort4 p;
            p.x = f2bf(av[i].x); p.y = f2bf(av[i].y);
            p.z = f2bf(av[i].z); p.w = f2bf(av[i].w);
            *(ushort4*)&Asf[row][kq] = p;
        }
#pragma unroll
        for (int i = 0; i < 2; ++i) {
            const int idx = i * 256 + t;
            const int n = idx >> 2, q = idx & 3;
            *(uint4*)&Bsb[n][q * 8] = bv[i];
        }
        __syncthreads();

        bf16x8 af[4], bfr[4];
#pragma unroll
        for (int mt = 0; mt < 4; ++mt)
            af[mt] = *(const bf16x8*)&Asf[wr + mt * 16 + lcol][lquad * 8];
#pragma unroll
        for (int nt = 0; nt < 4; ++nt)
            bfr[nt] = *(const bf16x8*)&Bsb[wc + nt * 16 + lcol][lquad * 8];
#pragma unroll
        for (int mt = 0; mt < 4; ++mt)
#pragma unroll
            for (int nt = 0; nt < 4; ++nt)
                acc[mt][nt] = __builtin_amdgcn_mfma_f32_16x16x32_bf16(af[mt], bfr[nt], acc[mt][nt], 0, 0, 0);
    }

    const int b0 = bnd[0], b1 = bnd[1], b2 = bnd[2];
    const int segBase = segRow[0];
#pragma unroll
    for (int nt = 0; nt < 4; ++nt) {
        const int col = wc + nt * 16 + lcol;
        const float bias = bm[cTile + col];
        float pm[4] = {0.f, 0.f, 0.f, 0.f};
#pragma unroll
        for (int mt = 0; mt < 4; ++mt) {
#pragma unroll
            for (int r = 0; r < 4; ++r) {
                const int lr = wr + mt * 16 + lquad * 4 + r;
                const int ls = (lr >= b0) + (lr >= b1) + (lr >= b2);
                const float v = fmaxf(acc[mt][nt][r] + bias, 0.f);
                pm[ls] = fmaxf(pm[ls], v);
            }
        }
#pragma unroll
        for (int ls = 0; ls < 4; ++ls)
            if (pm[ls] > 0.f) atomicMax(&Pmax[ls][col], __float_as_int(pm[ls]));
    }
    __syncthreads();
    for (int idx = t; idx < 4 * BN; idx += 256) {
        const int ls = idx >> 7, col = idx & 127;
        if (ls > 0 && bnd[ls - 1] >= BM) continue;
        const int seg = segBase + ls;
        const int v = Pmax[ls][col];
        const int gs = sse[seg], ge = sse[seg + 1];
        float* dst = &out[(size_t)seg * H + cTile + col];
        if (gs >= rowBase && ge <= rowBase + BM) *dst = __int_as_float(v);
        else atomicMax((int*)dst, v);
    }
}

extern "C" void kernel_launch(void* const* d_in, const int* in_sizes, int n_in,
                              void* d_out, int out_size, void* d_ws, size_t ws_size,
                              hipStream_t stream) {
    const float* hist_enc = (const float*)d_in[0];
    const float* pos      = (const float*)d_in[1];
    const int*   sse      = (const int*)  d_in[2];
    const float* Ws       = (const float*)d_in[3];
    const float* bs       = (const float*)d_in[4];
    const float* Wm       = (const float*)d_in[5];
    const float* bm       = (const float*)d_in[6];
    float*       out      = (float*)d_out;

    const size_t needWmT = (size_t)H * KD * 2;     // 655,360 B
    const size_t needSeg = (size_t)NR * 4;         // 409,600 B
    const size_t needRel = (size_t)NR * 2 * 4;     // 819,200 B
    unsigned short* WmT  = (unsigned short*)d_ws;
    int*            segA = (int*)  ((char*)d_ws + needWmT);
    float*          relA = (float*)((char*)d_ws + needWmT + needSeg);

    (void)hipMemsetAsync(out, 0, (size_t)out_size * sizeof(float), stream);

    if (ws_size >= needWmT + needSeg + needRel) {
        prep3<<<480, 256, 0, stream>>>(pos, sse, Wm, WmT, segA, relA);
        pool_tile32<<<(NR / RB) * 2, 256, 0, stream>>>(hist_enc, sse, segA, relA, Ws, bs, WmT, bm, out);
    } else {
        prep3<<<480, 256, 0, stream>>>(pos, sse, Wm, WmT, nullptr, nullptr);
        pool_mfma_fb<<<dim3(H / BN, NR / BM), 256, 0, stream>>>(hist_enc, pos, sse, Ws, bs, WmT, bm, out);
    }
}